// Round 2
// baseline (351.990 us; speedup 1.0000x reference)
//
#include <hip/hip_runtime.h>
#include <math.h>

// PhasorSample via type-2 NUFFT:
//   feat[n,c] = Re sum_{k in [-32,31], l in [0,63]} C[c,k,l]*w_l*e^{2pi i(k*u + l*v)}
// Steps (all on-device, every call):
//   1) phihat tables for the ES spread kernel (quadrature)
//   2) Chat = (pr + i*pi)*gauss*w / (phix(|k|)*phiy(l))           [deconvolution]
//   3) T[c,kk,Y] = sum_l Chat * e^{2pi i l Y/Gy}                  [y-DFT, small]
//   4) g[X,Y,c]  = Re sum_kk T * e^{2pi i k X/Gx}                 [x-DFT, small]
//   5) feat[n,c] = sum_{8x8 taps} g[Xi,Yj,c] * psi(px-Xi)*psi(py-Yj)
// Grid 128x256x16 fp32 = 2 MB (L2-resident). Aliasing err ~1e-7 (beta=18.4, J=8).

#define NPTS  262144
#define GX    128
#define GY    256
#define BETA  18.4f
#define PI_F      3.14159265358979323846f
#define TWO_PI_F  6.28318530717958647692f

// ws layout (bytes):
//   0        : phit[128] floats  ([0..32] = phix, [64..127] = phiy)
//   4096     : Chat[16*64*64] float2   (512 KB)
//   1048576  : T[16*64*256] float2     (2 MB)
//   3145728  : g[128*256*16] float     (2 MB)    total 5.25 MB of ws

// ---- 1) spread-kernel Fourier transform, trapezoid quadrature ----------------
__global__ void k_deconv(float* __restrict__ phit) {
    int b = blockIdx.x;                 // 0..32 -> x freq k=b ; 33..96 -> y freq l=b-33
    float xi; int idx;
    if (b < 33) { xi = (float)b * (1.0f / (float)GX); idx = b; }
    else        { xi = (float)(b - 33) * (1.0f / (float)GY); idx = 64 + (b - 33); }
    const int NQ = 1024;
    const float h = 8.0f / (float)NQ;
    float sum = 0.0f;
    for (int i = threadIdx.x; i <= NQ; i += blockDim.x) {
        float z  = -4.0f + h * (float)i;
        float t  = 0.25f * z;
        float s2 = fmaxf(1.0f - t * t, 0.0f);
        float psi = expf(BETA * (sqrtf(s2) - 1.0f));
        float w = (i == 0 || i == NQ) ? 0.5f : 1.0f;
        sum += w * psi * cosf(TWO_PI_F * xi * z);
    }
    __shared__ float red[256];
    red[threadIdx.x] = sum;
    __syncthreads();
    for (int s = 128; s > 0; s >>= 1) {
        if ((int)threadIdx.x < s) red[threadIdx.x] += red[threadIdx.x + s];
        __syncthreads();
    }
    if (threadIdx.x == 0) phit[idx] = red[0] * h;
}

// ---- 2) build deconvolved spectrum ------------------------------------------
__global__ void k_chat(const float* __restrict__ pr, const float* __restrict__ pim,
                       const float* __restrict__ gvar, const float* __restrict__ phit,
                       float2* __restrict__ chat) {
    int t  = blockIdx.x * 256 + threadIdx.x;      // c*4096 + kk*64 + l
    int l  = t & 63;
    int kk = (t >> 6) & 63;
    int k  = (kk < 32) ? kk : kk - 64;
    int ak = (k < 0) ? -k : k;
    float fx = (float)k * (1.0f / 512.0f);
    float fy = (float)l * (1.0f / 512.0f);
    float var = gvar[0];
    float gauss = expf(-2.0f * PI_F * PI_F * var * (fx * fx + fy * fy));
    float w = (l == 0) ? 1.0f : 2.0f;
    // NOTE: no Gx*Gy factor — y/x-DFT are plain sums and Poisson gives
    // e^{2pi i k u} ~ (1/phihat(k/G)) sum_X psi(px-X) e^{2pi i k X/G}.
    float scale = gauss * w / (phit[ak] * phit[64 + l]);
    chat[t] = make_float2(pr[t] * scale, pim[t] * scale);
}

// ---- 3) y-DFT: T[c,kk,Y] -----------------------------------------------------
__global__ void k_ydft(const float2* __restrict__ chat, float2* __restrict__ T) {
    int ck = blockIdx.x;                 // c*64 + kk  (1024 blocks)
    int Y  = threadIdx.x;                // 0..255
    const float2* crow = chat + ck * 64; // wave-uniform -> scalar loads
    float th = TWO_PI_F * (float)Y * (1.0f / (float)GY);
    float s1, c1;
    sincosf(th, &s1, &c1);
    float cr = 1.0f, sr = 0.0f, ar = 0.0f, ai = 0.0f;
    for (int l = 0; l < 64; ++l) {
        float2 cv = crow[l];
        ar = fmaf(cv.x, cr, ar); ar = fmaf(-cv.y, sr, ar);
        ai = fmaf(cv.x, sr, ai); ai = fmaf(cv.y, cr, ai);
        float cn = fmaf(cr, c1, -sr * s1);
        float sn = fmaf(sr, c1,  cr * s1);
        cr = cn; sr = sn;
    }
    T[ck * 256 + Y] = make_float2(ar, ai);
}

// ---- 4) x-DFT (real part): g[X,Y,c] -----------------------------------------
__global__ void k_xdft(const float2* __restrict__ T, float* __restrict__ g) {
    int X = blockIdx.x;                  // 0..127
    int Y = threadIdx.x;                 // 0..255
    float th = TWO_PI_F * (float)X * (1.0f / (float)GX);
    float s1, c1;
    sincosf(th, &s1, &c1);
    float sgn = (X & 1) ? -1.0f : 1.0f;  // e^{2pi i(kk-64)X/128} = w^kk * (-1)^X
    float cr = 1.0f, sr = 0.0f;
    float acc[16];
#pragma unroll
    for (int c = 0; c < 16; ++c) acc[c] = 0.0f;
    for (int kk = 0; kk < 64; ++kk) {
        float fr = (kk >= 32) ? cr * sgn : cr;
        float fi = (kk >= 32) ? sr * sgn : sr;
#pragma unroll
        for (int c = 0; c < 16; ++c) {
            float2 tv = T[(c * 64 + kk) * 256 + Y];   // coalesced over Y
            acc[c] = fmaf(tv.x, fr, acc[c]);
            acc[c] = fmaf(-tv.y, fi, acc[c]);         // Re(T * e^{i phi})
        }
        float cn = fmaf(cr, c1, -sr * s1);
        float sn = fmaf(sr, c1,  cr * s1);
        cr = cn; sr = sn;
    }
    float4* dst = (float4*)(g + ((size_t)X * 256 + (size_t)Y) * 16);
    dst[0] = make_float4(acc[0],  acc[1],  acc[2],  acc[3]);
    dst[1] = make_float4(acc[4],  acc[5],  acc[6],  acc[7]);
    dst[2] = make_float4(acc[8],  acc[9],  acc[10], acc[11]);
    dst[3] = make_float4(acc[12], acc[13], acc[14], acc[15]);
}

// ---- 5) per-point 8x8-tap interpolation (the hot kernel) --------------------
__global__ __launch_bounds__(256) void k_sample(const float2* __restrict__ coord,
                                                const float* __restrict__ g,
                                                float* __restrict__ out) {
    int n = blockIdx.x * 256 + threadIdx.x;
    float2 uv = coord[n];
    float px = uv.x * (float)GX;
    float py = uv.y * (float)GY;
    int ix0 = (int)floorf(px) - 3;
    int iy0 = (int)floorf(py) - 3;
    float wx[8], wy[8];
#pragma unroll
    for (int i = 0; i < 8; ++i) {
        float zx = px - (float)(ix0 + i);            // in (-4, 4)
        float tx = 0.25f * zx;
        float sx2 = fmaxf(1.0f - tx * tx, 0.0f);
        wx[i] = __expf(BETA * (sqrtf(sx2) - 1.0f));
        float zy = py - (float)(iy0 + i);
        float ty = 0.25f * zy;
        float sy2 = fmaxf(1.0f - ty * ty, 0.0f);
        wy[i] = __expf(BETA * (sqrtf(sy2) - 1.0f));
    }
    float4 a0 = make_float4(0.f, 0.f, 0.f, 0.f), a1 = a0, a2 = a0, a3 = a0;
#pragma unroll
    for (int i = 0; i < 8; ++i) {
        const float* row = g + (size_t)((ix0 + i) & (GX - 1)) * (GY * 16);
        float wxi = wx[i];
#pragma unroll
        for (int j = 0; j < 8; ++j) {
            const float4* p = (const float4*)(row + ((iy0 + j) & (GY - 1)) * 16);
            float w = wxi * wy[j];
            float4 v0 = p[0], v1 = p[1], v2 = p[2], v3 = p[3];
            a0.x = fmaf(w, v0.x, a0.x); a0.y = fmaf(w, v0.y, a0.y);
            a0.z = fmaf(w, v0.z, a0.z); a0.w = fmaf(w, v0.w, a0.w);
            a1.x = fmaf(w, v1.x, a1.x); a1.y = fmaf(w, v1.y, a1.y);
            a1.z = fmaf(w, v1.z, a1.z); a1.w = fmaf(w, v1.w, a1.w);
            a2.x = fmaf(w, v2.x, a2.x); a2.y = fmaf(w, v2.y, a2.y);
            a2.z = fmaf(w, v2.z, a2.z); a2.w = fmaf(w, v2.w, a2.w);
            a3.x = fmaf(w, v3.x, a3.x); a3.y = fmaf(w, v3.y, a3.y);
            a3.z = fmaf(w, v3.z, a3.z); a3.w = fmaf(w, v3.w, a3.w);
        }
    }
    float4* o = (float4*)(out + (size_t)n * 16);
    o[0] = a0; o[1] = a1; o[2] = a2; o[3] = a3;
}

extern "C" void kernel_launch(void* const* d_in, const int* in_sizes, int n_in,
                              void* d_out, int out_size, void* d_ws, size_t ws_size,
                              hipStream_t stream) {
    const float* coord = (const float*)d_in[0];   // [N,2]
    const float* preal = (const float*)d_in[1];   // [1,16,64,64]
    const float* pimag = (const float*)d_in[2];
    const float* gvar  = (const float*)d_in[3];   // scalar

    char*   ws   = (char*)d_ws;
    float*  phit = (float*)(ws + 0);
    float2* chat = (float2*)(ws + 4096);
    float2* T    = (float2*)(ws + 1048576);
    float*  g    = (float*)(ws + 3145728);
    float*  out  = (float*)d_out;

    hipLaunchKernelGGL(k_deconv, dim3(97),        dim3(256), 0, stream, phit);
    hipLaunchKernelGGL(k_chat,   dim3(256),       dim3(256), 0, stream, preal, pimag, gvar, phit, chat);
    hipLaunchKernelGGL(k_ydft,   dim3(1024),      dim3(256), 0, stream, chat, T);
    hipLaunchKernelGGL(k_xdft,   dim3(128),       dim3(256), 0, stream, T, g);
    hipLaunchKernelGGL(k_sample, dim3(NPTS/256),  dim3(256), 0, stream, (const float2*)coord, g, out);
}

// Round 5
// 182.763 us; speedup vs baseline: 1.9259x; 1.9259x over previous
//
#include <hip/hip_runtime.h>
#include <math.h>

// PhasorSample via type-2 NUFFT:
//   feat[n,c] = Re sum_{k in [-32,31], l in [0,63]} C[c,k,l]*w_l*e^{2pi i(k*u + l*v)}
// Steps (all on-device, every call):
//   1) phihat tables for the ES spread kernel (quadrature)
//   2+3) T[c,kk,Y] = sum_l Chat(l)*e^{2pi i l Y/Gy}   (deconv fused into y-DFT)
//   4) g[X,Y,c]  = Re sum_kk T * e^{2pi i k X/Gx}
//   5) feat[n,c] = sum_{8x8 taps} g[Xi,Yj,c] * psi(px-Xi)*psi(py-Yj)
//      -- gather restructured: 8 lanes per point, lane=channel-pair, so each
//         point-tap is ONE 64B line touched by ONE float2 instruction.
// Grid 128x256x16 fp32 = 2 MB (L2-resident). Aliasing err ~1e-7 (beta=18.4, J=8).

#define NPTS  262144
#define GX    128
#define GY    256
#define BETA  18.4f
#define PI_F      3.14159265358979323846f
#define TWO_PI_F  6.28318530717958647692f

// ws layout (bytes):
//   0        : phit[128] floats  ([0..32] = phix, [64..127] = phiy)
//   1048576  : T[16*64*256] float2     (2 MB)
//   3145728  : g[128*256*16] float     (2 MB)

// ---- 1) spread-kernel Fourier transform, trapezoid quadrature ----------------
__global__ void k_deconv(float* __restrict__ phit) {
    int b = blockIdx.x;                 // 0..32 -> x freq k=b ; 33..96 -> y freq l=b-33
    float xi; int idx;
    if (b < 33) { xi = (float)b * (1.0f / (float)GX); idx = b; }
    else        { xi = (float)(b - 33) * (1.0f / (float)GY); idx = 64 + (b - 33); }
    const int NQ = 1024;
    const float h = 8.0f / (float)NQ;
    float sum = 0.0f;
    for (int i = threadIdx.x; i <= NQ; i += blockDim.x) {
        float z  = -4.0f + h * (float)i;
        float t  = 0.25f * z;
        float s2 = fmaxf(1.0f - t * t, 0.0f);
        float psi = expf(BETA * (sqrtf(s2) - 1.0f));
        float w = (i == 0 || i == NQ) ? 0.5f : 1.0f;
        sum += w * psi * cosf(TWO_PI_F * xi * z);
    }
    __shared__ float red[256];
    red[threadIdx.x] = sum;
    __syncthreads();
    for (int s = 128; s > 0; s >>= 1) {
        if ((int)threadIdx.x < s) red[threadIdx.x] += red[threadIdx.x + s];
        __syncthreads();
    }
    if (threadIdx.x == 0) phit[idx] = red[0] * h;
}

// ---- 2+3) fused deconv + y-DFT: T[c,kk,Y] -----------------------------------
__global__ void k_ydft(const float* __restrict__ pr, const float* __restrict__ pim,
                       const float* __restrict__ gvar, const float* __restrict__ phit,
                       float2* __restrict__ T) {
    int ck = blockIdx.x;                 // c*64 + kk  (1024 blocks)
    int kk = ck & 63;
    int k  = (kk < 32) ? kk : kk - 64;
    int ak = (k < 0) ? -k : k;
    __shared__ float2 cs[64];
    if (threadIdx.x < 64) {
        int l = threadIdx.x;
        float fx = (float)k * (1.0f / 512.0f);
        float fy = (float)l * (1.0f / 512.0f);
        float var = gvar[0];
        float gauss = expf(-2.0f * PI_F * PI_F * var * (fx * fx + fy * fy));
        float w = (l == 0) ? 1.0f : 2.0f;
        // No Gx*Gy factor: Poisson gives e^{2pi i k u} ~ (1/phihat) * sum_X psi*e^{...}
        float scale = gauss * w / (phit[ak] * phit[64 + l]);
        int t = ck * 64 + l;
        cs[l] = make_float2(pr[t] * scale, pim[t] * scale);
    }
    __syncthreads();
    int Y = threadIdx.x;                 // 0..255
    float th = TWO_PI_F * (float)Y * (1.0f / (float)GY);
    float s1, c1;
    sincosf(th, &s1, &c1);
    float cr = 1.0f, sr = 0.0f, ar = 0.0f, ai = 0.0f;
    for (int l = 0; l < 64; ++l) {
        float2 cv = cs[l];
        ar = fmaf(cv.x, cr, ar); ar = fmaf(-cv.y, sr, ar);
        ai = fmaf(cv.x, sr, ai); ai = fmaf(cv.y, cr, ai);
        float cn = fmaf(cr, c1, -sr * s1);
        float sn = fmaf(sr, c1,  cr * s1);
        cr = cn; sr = sn;
    }
    T[ck * 256 + Y] = make_float2(ar, ai);
}

// ---- 4) x-DFT (real part): g[X,Y,c] -----------------------------------------
__global__ void k_xdft(const float2* __restrict__ T, float* __restrict__ g) {
    int X = blockIdx.x;                  // 0..127
    int Y = threadIdx.x;                 // 0..255
    float th = TWO_PI_F * (float)X * (1.0f / (float)GX);
    float s1, c1;
    sincosf(th, &s1, &c1);
    float sgn = (X & 1) ? -1.0f : 1.0f;  // e^{2pi i(kk-64)X/128} = w^kk * (-1)^X
    float cr = 1.0f, sr = 0.0f;
    float acc[16];
#pragma unroll
    for (int c = 0; c < 16; ++c) acc[c] = 0.0f;
    for (int kk = 0; kk < 64; ++kk) {
        float fr = (kk >= 32) ? cr * sgn : cr;
        float fi = (kk >= 32) ? sr * sgn : sr;
#pragma unroll
        for (int c = 0; c < 16; ++c) {
            float2 tv = T[(c * 64 + kk) * 256 + Y];   // coalesced over Y
            acc[c] = fmaf(tv.x, fr, acc[c]);
            acc[c] = fmaf(-tv.y, fi, acc[c]);         // Re(T * e^{i phi})
        }
        float cn = fmaf(cr, c1, -sr * s1);
        float sn = fmaf(sr, c1,  cr * s1);
        cr = cn; sr = sn;
    }
    float4* dst = (float4*)(g + ((size_t)X * 256 + (size_t)Y) * 16);
    dst[0] = make_float4(acc[0],  acc[1],  acc[2],  acc[3]);
    dst[1] = make_float4(acc[4],  acc[5],  acc[6],  acc[7]);
    dst[2] = make_float4(acc[8],  acc[9],  acc[10], acc[11]);
    dst[3] = make_float4(acc[12], acc[13], acc[14], acc[15]);
}

// ---- 5) per-point interpolation, 8 lanes per point (lane = channel pair) ----
__global__ __launch_bounds__(256) void k_sample(const float2* __restrict__ coord,
                                                const float* __restrict__ g,
                                                float* __restrict__ out) {
    int n   = blockIdx.x * 32 + (threadIdx.x >> 3);   // 32 points per block
    int sub = threadIdx.x & 7;                        // channel pair 2*sub, 2*sub+1
    float2 uv = coord[n];                             // broadcast across 8 lanes
    float px = uv.x * (float)GX;
    float py = uv.y * (float)GY;
    int ix0 = (int)floorf(px) - 3;
    int iy0 = (int)floorf(py) - 3;
    float wx[8], wy[8];
#pragma unroll
    for (int i = 0; i < 8; ++i) {                     // replicated x8 lanes (VALU idle)
        float zx = px - (float)(ix0 + i);
        float tx = 0.25f * zx;
        float sx2 = fmaxf(1.0f - tx * tx, 0.0f);
        wx[i] = __expf(BETA * (sqrtf(sx2) - 1.0f));
        float zy = py - (float)(iy0 + i);
        float ty = 0.25f * zy;
        float sy2 = fmaxf(1.0f - ty * ty, 0.0f);
        wy[i] = __expf(BETA * (sqrtf(sy2) - 1.0f));
    }
    const float* gp = g + sub * 2;
    float acc0 = 0.0f, acc1 = 0.0f;
#pragma unroll
    for (int i = 0; i < 8; ++i) {
        const float* rowp = gp + (size_t)((ix0 + i) & (GX - 1)) * (GY * 16);
        float wxi = wx[i];
#pragma unroll
        for (int j = 0; j < 8; ++j) {
            float2 v = *(const float2*)(rowp + ((iy0 + j) & (GY - 1)) * 16);
            float w = wxi * wy[j];
            acc0 = fmaf(w, v.x, acc0);
            acc1 = fmaf(w, v.y, acc1);
        }
    }
    *(float2*)(out + (size_t)n * 16 + sub * 2) = make_float2(acc0, acc1);
}

extern "C" void kernel_launch(void* const* d_in, const int* in_sizes, int n_in,
                              void* d_out, int out_size, void* d_ws, size_t ws_size,
                              hipStream_t stream) {
    const float* coord = (const float*)d_in[0];   // [N,2]
    const float* preal = (const float*)d_in[1];   // [1,16,64,64]
    const float* pimag = (const float*)d_in[2];
    const float* gvar  = (const float*)d_in[3];   // scalar

    char*   ws   = (char*)d_ws;
    float*  phit = (float*)(ws + 0);
    float2* T    = (float2*)(ws + 1048576);
    float*  g    = (float*)(ws + 3145728);
    float*  out  = (float*)d_out;

    hipLaunchKernelGGL(k_deconv, dim3(97),        dim3(256), 0, stream, phit);
    hipLaunchKernelGGL(k_ydft,   dim3(1024),      dim3(256), 0, stream, preal, pimag, gvar, phit, T);
    hipLaunchKernelGGL(k_xdft,   dim3(128),       dim3(256), 0, stream, T, g);
    hipLaunchKernelGGL(k_sample, dim3(NPTS/32),   dim3(256), 0, stream, (const float2*)coord, g, out);
}

// Round 6
// 126.275 us; speedup vs baseline: 2.7875x; 1.4473x over previous
//
#include <hip/hip_runtime.h>
#include <math.h>

// PhasorSample via type-2 NUFFT:
//   feat[n,c] = Re sum_{k in [-32,31], l in [0,63]} C[c,k,l]*w_l*e^{2pi i(k*u + l*v)}
// Steps:
//   1) phihat tables for the ES spread kernel (quadrature over [-3,3], J=6)
//   2+3) T[c,kk,Y] = sum_l Chat(l)*e^{2pi i l Y/Gy}   (deconv fused into y-DFT)
//   4) g[X,Y,c]  = Re sum_kk T * e^{2pi i k X/Gx}     (4 channels/thread, 512 blocks)
//   5) feat[n,c] = sum_{6x6 taps} g[Xi,Yj,c] * psi(px-Xi)*psi(py-Yj)
//      8 lanes per point (lane = channel pair): each point-tap is ONE 64B line
//      touched by ONE float2 instruction.
// Grid 128x256x16 fp32 = 2 MB (L2-resident). J=6, beta=13.8 -> err ~3e-5 rel.

#define NPTS  262144
#define GX    128
#define GY    256
#define BETA  13.8f
#define PI_F      3.14159265358979323846f
#define TWO_PI_F  6.28318530717958647692f

// ws layout (bytes):
//   0        : phit[128] floats  ([0..32] = phix, [64..127] = phiy)
//   1048576  : T[16*64*256] float2     (2 MB)
//   3145728  : g[128*256*16] float     (2 MB)

// ---- 1) spread-kernel Fourier transform, trapezoid quadrature over [-3,3] ---
__global__ void k_deconv(float* __restrict__ phit) {
    int b = blockIdx.x;                 // 0..32 -> x freq k=b ; 33..96 -> y freq l=b-33
    float xi; int idx;
    if (b < 33) { xi = (float)b * (1.0f / (float)GX); idx = b; }
    else        { xi = (float)(b - 33) * (1.0f / (float)GY); idx = 64 + (b - 33); }
    const int NQ = 1024;
    const float h = 6.0f / (float)NQ;
    float sum = 0.0f;
    for (int i = threadIdx.x; i <= NQ; i += blockDim.x) {
        float z  = -3.0f + h * (float)i;
        float t  = z * (1.0f / 3.0f);
        float s2 = fmaxf(1.0f - t * t, 0.0f);
        float psi = expf(BETA * (sqrtf(s2) - 1.0f));
        float w = (i == 0 || i == NQ) ? 0.5f : 1.0f;
        sum += w * psi * cosf(TWO_PI_F * xi * z);
    }
    __shared__ float red[256];
    red[threadIdx.x] = sum;
    __syncthreads();
    for (int s = 128; s > 0; s >>= 1) {
        if ((int)threadIdx.x < s) red[threadIdx.x] += red[threadIdx.x + s];
        __syncthreads();
    }
    if (threadIdx.x == 0) phit[idx] = red[0] * h;
}

// ---- 2+3) fused deconv + y-DFT: T[c,kk,Y] -----------------------------------
__global__ void k_ydft(const float* __restrict__ pr, const float* __restrict__ pim,
                       const float* __restrict__ gvar, const float* __restrict__ phit,
                       float2* __restrict__ T) {
    int ck = blockIdx.x;                 // c*64 + kk  (1024 blocks)
    int kk = ck & 63;
    int k  = (kk < 32) ? kk : kk - 64;
    int ak = (k < 0) ? -k : k;
    __shared__ float2 cs[64];
    if (threadIdx.x < 64) {
        int l = threadIdx.x;
        float fx = (float)k * (1.0f / 512.0f);
        float fy = (float)l * (1.0f / 512.0f);
        float var = gvar[0];
        float gauss = expf(-2.0f * PI_F * PI_F * var * (fx * fx + fy * fy));
        float w = (l == 0) ? 1.0f : 2.0f;
        // No Gx*Gy factor: Poisson gives e^{2pi i k u} ~ (1/phihat) * sum_X psi*e^{...}
        float scale = gauss * w / (phit[ak] * phit[64 + l]);
        int t = ck * 64 + l;
        cs[l] = make_float2(pr[t] * scale, pim[t] * scale);
    }
    __syncthreads();
    int Y = threadIdx.x;                 // 0..255
    float th = TWO_PI_F * (float)Y * (1.0f / (float)GY);
    float s1, c1;
    sincosf(th, &s1, &c1);
    float cr = 1.0f, sr = 0.0f, ar = 0.0f, ai = 0.0f;
    for (int l = 0; l < 64; ++l) {
        float2 cv = cs[l];
        ar = fmaf(cv.x, cr, ar); ar = fmaf(-cv.y, sr, ar);
        ai = fmaf(cv.x, sr, ai); ai = fmaf(cv.y, cr, ai);
        float cn = fmaf(cr, c1, -sr * s1);
        float sn = fmaf(sr, c1,  cr * s1);
        cr = cn; sr = sn;
    }
    T[ck * 256 + Y] = make_float2(ar, ai);
}

// ---- 4) x-DFT (real part): g[X,Y,c], 4 channels per thread ------------------
__global__ void k_xdft(const float2* __restrict__ T, float* __restrict__ g) {
    int X  = blockIdx.x;                 // 0..127
    int c0 = blockIdx.y * 4;             // channel group
    int Y  = threadIdx.x;                // 0..255
    float th = TWO_PI_F * (float)X * (1.0f / (float)GX);
    float s1, c1;
    sincosf(th, &s1, &c1);
    float sgn = (X & 1) ? -1.0f : 1.0f;  // e^{2pi i(kk-64)X/128} = w^kk * (-1)^X
    float cr = 1.0f, sr = 0.0f;
    float a0 = 0.f, a1 = 0.f, a2 = 0.f, a3 = 0.f;
    for (int kk = 0; kk < 64; ++kk) {
        float fr = (kk >= 32) ? cr * sgn : cr;
        float fi = (kk >= 32) ? sr * sgn : sr;
        float2 t0 = T[((c0 + 0) * 64 + kk) * 256 + Y];   // coalesced over Y
        float2 t1 = T[((c0 + 1) * 64 + kk) * 256 + Y];
        float2 t2 = T[((c0 + 2) * 64 + kk) * 256 + Y];
        float2 t3 = T[((c0 + 3) * 64 + kk) * 256 + Y];
        a0 = fmaf(t0.x, fr, a0); a0 = fmaf(-t0.y, fi, a0);
        a1 = fmaf(t1.x, fr, a1); a1 = fmaf(-t1.y, fi, a1);
        a2 = fmaf(t2.x, fr, a2); a2 = fmaf(-t2.y, fi, a2);
        a3 = fmaf(t3.x, fr, a3); a3 = fmaf(-t3.y, fi, a3);
        float cn = fmaf(cr, c1, -sr * s1);
        float sn = fmaf(sr, c1,  cr * s1);
        cr = cn; sr = sn;
    }
    *(float4*)(g + ((size_t)X * 256 + (size_t)Y) * 16 + c0) = make_float4(a0, a1, a2, a3);
}

// ---- 5) per-point interpolation, 8 lanes per point, 6x6 taps ----------------
__global__ __launch_bounds__(256) void k_sample(const float2* __restrict__ coord,
                                                const float* __restrict__ g,
                                                float* __restrict__ out) {
    int n   = blockIdx.x * 32 + (threadIdx.x >> 3);   // 32 points per block
    int sub = threadIdx.x & 7;                        // channel pair 2*sub, 2*sub+1
    float2 uv = coord[n];                             // broadcast across 8 lanes
    float px = uv.x * (float)GX;
    float py = uv.y * (float)GY;
    int ix0 = (int)floorf(px) - 2;
    int iy0 = (int)floorf(py) - 2;
    float wx[6], wy[6];
#pragma unroll
    for (int i = 0; i < 6; ++i) {                     // replicated x8 lanes
        float zx = px - (float)(ix0 + i);             // in (-3, 3)
        float tx = zx * (1.0f / 3.0f);
        float sx2 = fmaxf(1.0f - tx * tx, 0.0f);
        wx[i] = __expf(BETA * (sqrtf(sx2) - 1.0f));
        float zy = py - (float)(iy0 + i);
        float ty = zy * (1.0f / 3.0f);
        float sy2 = fmaxf(1.0f - ty * ty, 0.0f);
        wy[i] = __expf(BETA * (sqrtf(sy2) - 1.0f));
    }
    int yo[6];
#pragma unroll
    for (int j = 0; j < 6; ++j)
        yo[j] = ((iy0 + j) & (GY - 1)) * 16 + sub * 2;
    float acc0 = 0.0f, acc1 = 0.0f;
#pragma unroll
    for (int i = 0; i < 6; ++i) {
        const float* rowp = g + (size_t)(((ix0 + i) & (GX - 1)) * (GY * 16));
        float wxi = wx[i];
#pragma unroll
        for (int j = 0; j < 6; ++j) {
            float2 v = *(const float2*)(rowp + yo[j]);
            float w = wxi * wy[j];
            acc0 = fmaf(w, v.x, acc0);
            acc1 = fmaf(w, v.y, acc1);
        }
    }
    *(float2*)(out + (size_t)n * 16 + sub * 2) = make_float2(acc0, acc1);
}

extern "C" void kernel_launch(void* const* d_in, const int* in_sizes, int n_in,
                              void* d_out, int out_size, void* d_ws, size_t ws_size,
                              hipStream_t stream) {
    const float* coord = (const float*)d_in[0];   // [N,2]
    const float* preal = (const float*)d_in[1];   // [1,16,64,64]
    const float* pimag = (const float*)d_in[2];
    const float* gvar  = (const float*)d_in[3];   // scalar

    char*   ws   = (char*)d_ws;
    float*  phit = (float*)(ws + 0);
    float2* T    = (float2*)(ws + 1048576);
    float*  g    = (float*)(ws + 3145728);
    float*  out  = (float*)d_out;

    hipLaunchKernelGGL(k_deconv, dim3(97),          dim3(256), 0, stream, phit);
    hipLaunchKernelGGL(k_ydft,   dim3(1024),        dim3(256), 0, stream, preal, pimag, gvar, phit, T);
    hipLaunchKernelGGL(k_xdft,   dim3(128, 4),      dim3(256), 0, stream, T, g);
    hipLaunchKernelGGL(k_sample, dim3(NPTS/32),     dim3(256), 0, stream, (const float2*)coord, g, out);
}

// Round 10
// 106.663 us; speedup vs baseline: 3.3000x; 1.1839x over previous
//
#include <hip/hip_runtime.h>
#include <hip/hip_fp16.h>
#include <math.h>

// PhasorSample via type-2 NUFFT:
//   feat[n,c] = Re sum_{k in [-32,31], l in [0,63]} C[c,k,l]*w_l*e^{2pi i(k*u + l*v)}
// Steps:
//   1) phihat tables for the ES spread kernel (quadrature over [-2.5,2.5], J=5)
//   2+3) T[c,kk,Y] = sum_l Chat(l)*e^{2pi i l Y/Gy}   (deconv fused into y-DFT)
//   4) g[X,Y,c]  = Re sum_kk T * e^{2pi i k X/Gx}     -> packed to fp16
//   5) feat[n,c] = sum_{5x5 taps} g[Xi,Yj,c] * psi(px-Xi)*psi(py-Yj)
//      4 lanes per point (lane = 4 channels, one 8B fp16 load per tap).
// Grid 128x256x16 fp16 = 1 MB (L2-resident). J=5, beta=11.5 -> err ~1e-4 rel.
// k_sample is L2-request-bound (~4us per M line-requests): requests = pts*taps.

#define NPTS  262144
#define GX    128
#define GY    256
#define BETA  11.5f
#define PI_F      3.14159265358979323846f
#define TWO_PI_F  6.28318530717958647692f

// ws layout (bytes):
//   0        : phit[128] floats  ([0..32] = phix, [64..127] = phiy)
//   1048576  : T[16*64*256] float2     (2 MB)
//   3145728  : gh[128*256*16] __half   (1 MB)

// ---- 1) spread-kernel Fourier transform, trapezoid quadrature over [-2.5,2.5]
__global__ void k_deconv(float* __restrict__ phit) {
    int b = blockIdx.x;                 // 0..32 -> x freq k=b ; 33..96 -> y freq l=b-33
    float xi; int idx;
    if (b < 33) { xi = (float)b * (1.0f / (float)GX); idx = b; }
    else        { xi = (float)(b - 33) * (1.0f / (float)GY); idx = 64 + (b - 33); }
    const int NQ = 1024;
    const float h = 5.0f / (float)NQ;
    float sum = 0.0f;
    for (int i = threadIdx.x; i <= NQ; i += blockDim.x) {
        float z  = -2.5f + h * (float)i;
        float t  = z * 0.4f;
        float s2 = fmaxf(1.0f - t * t, 0.0f);
        float psi = expf(BETA * (sqrtf(s2) - 1.0f));
        float w = (i == 0 || i == NQ) ? 0.5f : 1.0f;
        sum += w * psi * cosf(TWO_PI_F * xi * z);
    }
    __shared__ float red[256];
    red[threadIdx.x] = sum;
    __syncthreads();
    for (int s = 128; s > 0; s >>= 1) {
        if ((int)threadIdx.x < s) red[threadIdx.x] += red[threadIdx.x + s];
        __syncthreads();
    }
    if (threadIdx.x == 0) phit[idx] = red[0] * h;
}

// ---- 2+3) fused deconv + y-DFT: T[c,kk,Y] -----------------------------------
__global__ void k_ydft(const float* __restrict__ pr, const float* __restrict__ pim,
                       const float* __restrict__ gvar, const float* __restrict__ phit,
                       float2* __restrict__ T) {
    int ck = blockIdx.x;                 // c*64 + kk  (1024 blocks)
    int kk = ck & 63;
    int k  = (kk < 32) ? kk : kk - 64;
    int ak = (k < 0) ? -k : k;
    __shared__ float2 cs[64];
    if (threadIdx.x < 64) {
        int l = threadIdx.x;
        float fx = (float)k * (1.0f / 512.0f);
        float fy = (float)l * (1.0f / 512.0f);
        float var = gvar[0];
        float gauss = expf(-2.0f * PI_F * PI_F * var * (fx * fx + fy * fy));
        float w = (l == 0) ? 1.0f : 2.0f;
        // No Gx*Gy factor: Poisson gives e^{2pi i k u} ~ (1/phihat) * sum_X psi*e^{...}
        float scale = gauss * w / (phit[ak] * phit[64 + l]);
        int t = ck * 64 + l;
        cs[l] = make_float2(pr[t] * scale, pim[t] * scale);
    }
    __syncthreads();
    int Y = threadIdx.x;                 // 0..255
    float th = TWO_PI_F * (float)Y * (1.0f / (float)GY);
    float s1, c1;
    sincosf(th, &s1, &c1);
    float cr = 1.0f, sr = 0.0f, ar = 0.0f, ai = 0.0f;
    for (int l = 0; l < 64; ++l) {
        float2 cv = cs[l];
        ar = fmaf(cv.x, cr, ar); ar = fmaf(-cv.y, sr, ar);
        ai = fmaf(cv.x, sr, ai); ai = fmaf(cv.y, cr, ai);
        float cn = fmaf(cr, c1, -sr * s1);
        float sn = fmaf(sr, c1,  cr * s1);
        cr = cn; sr = sn;
    }
    T[ck * 256 + Y] = make_float2(ar, ai);
}

// ---- 4) x-DFT (real part) -> fp16 grid, 4 channels per thread ---------------
__global__ void k_xdft(const float2* __restrict__ T, __half* __restrict__ gh) {
    int X  = blockIdx.x;                 // 0..127
    int c0 = blockIdx.y * 4;             // channel group
    int Y  = threadIdx.x;                // 0..255
    float th = TWO_PI_F * (float)X * (1.0f / (float)GX);
    float s1, c1;
    sincosf(th, &s1, &c1);
    float sgn = (X & 1) ? -1.0f : 1.0f;  // e^{2pi i(kk-64)X/128} = w^kk * (-1)^X
    float cr = 1.0f, sr = 0.0f;
    float a0 = 0.f, a1 = 0.f, a2 = 0.f, a3 = 0.f;
    for (int kk = 0; kk < 64; ++kk) {
        float fr = (kk >= 32) ? cr * sgn : cr;
        float fi = (kk >= 32) ? sr * sgn : sr;
        float2 t0 = T[((c0 + 0) * 64 + kk) * 256 + Y];   // coalesced over Y
        float2 t1 = T[((c0 + 1) * 64 + kk) * 256 + Y];
        float2 t2 = T[((c0 + 2) * 64 + kk) * 256 + Y];
        float2 t3 = T[((c0 + 3) * 64 + kk) * 256 + Y];
        a0 = fmaf(t0.x, fr, a0); a0 = fmaf(-t0.y, fi, a0);
        a1 = fmaf(t1.x, fr, a1); a1 = fmaf(-t1.y, fi, a1);
        a2 = fmaf(t2.x, fr, a2); a2 = fmaf(-t2.y, fi, a2);
        a3 = fmaf(t3.x, fr, a3); a3 = fmaf(-t3.y, fi, a3);
        float cn = fmaf(cr, c1, -sr * s1);
        float sn = fmaf(sr, c1,  cr * s1);
        cr = cn; sr = sn;
    }
    union { __half2 h[2]; float2 f; } u;
    u.h[0] = __floats2half2_rn(a0, a1);
    u.h[1] = __floats2half2_rn(a2, a3);
    // byte offset of cell (X,Y), channel c0: X*8192 + Y*32 + c0*2
    *(float2*)((char*)gh + (size_t)X * 8192 + (size_t)Y * 32 + (size_t)c0 * 2) = u.f;
}

// ---- 5) per-point interpolation: 4 lanes/point, 5x5 taps, fp16 grid ---------
__global__ __launch_bounds__(256) void k_sample(const float2* __restrict__ coord,
                                                const __half* __restrict__ gh,
                                                float* __restrict__ out) {
    int n   = blockIdx.x * 64 + (threadIdx.x >> 2);   // 64 points per block
    int sub = threadIdx.x & 3;                        // channels 4*sub .. 4*sub+3
    float2 uv = coord[n];                             // broadcast across 4 lanes
    float px = uv.x * (float)GX;
    float py = uv.y * (float)GY;
    int ix0 = (int)floorf(px + 0.5f) - 2;             // taps centered: z in (-2.5,2.5)
    int iy0 = (int)floorf(py + 0.5f) - 2;
    float wx[5], wy[5];
#pragma unroll
    for (int i = 0; i < 5; ++i) {                     // replicated x4 lanes
        float zx = px - (float)(ix0 + i);
        float tx = zx * 0.4f;
        float sx2 = fmaxf(1.0f - tx * tx, 0.0f);
        wx[i] = __expf(BETA * (sqrtf(sx2) - 1.0f));
        float zy = py - (float)(iy0 + i);
        float ty = zy * 0.4f;
        float sy2 = fmaxf(1.0f - ty * ty, 0.0f);
        wy[i] = __expf(BETA * (sqrtf(sy2) - 1.0f));
    }
    int yo[5];
#pragma unroll
    for (int j = 0; j < 5; ++j)
        yo[j] = ((iy0 + j) & (GY - 1)) * 32 + sub * 8;   // byte offsets
    float a0 = 0.f, a1 = 0.f, a2 = 0.f, a3 = 0.f;
#pragma unroll
    for (int i = 0; i < 5; ++i) {
        const char* rowp = (const char*)gh + (size_t)(((ix0 + i) & (GX - 1)) * 8192);
        float wxi = wx[i];
#pragma unroll
        for (int j = 0; j < 5; ++j) {
            float2 raw = *(const float2*)(rowp + yo[j]);     // one 8B load = 4 fp16 ch
            __half2 h01 = *reinterpret_cast<const __half2*>(&raw.x);
            __half2 h23 = *reinterpret_cast<const __half2*>(&raw.y);
            float2 v01 = __half22float2(h01);
            float2 v23 = __half22float2(h23);
            float w = wxi * wy[j];
            a0 = fmaf(w, v01.x, a0);
            a1 = fmaf(w, v01.y, a1);
            a2 = fmaf(w, v23.x, a2);
            a3 = fmaf(w, v23.y, a3);
        }
    }
    *(float4*)(out + (size_t)n * 16 + sub * 4) = make_float4(a0, a1, a2, a3);
}

extern "C" void kernel_launch(void* const* d_in, const int* in_sizes, int n_in,
                              void* d_out, int out_size, void* d_ws, size_t ws_size,
                              hipStream_t stream) {
    const float* coord = (const float*)d_in[0];   // [N,2]
    const float* preal = (const float*)d_in[1];   // [1,16,64,64]
    const float* pimag = (const float*)d_in[2];
    const float* gvar  = (const float*)d_in[3];   // scalar

    char*   ws   = (char*)d_ws;
    float*  phit = (float*)(ws + 0);
    float2* T    = (float2*)(ws + 1048576);
    __half* gh   = (__half*)(ws + 3145728);
    float*  out  = (float*)d_out;

    hipLaunchKernelGGL(k_deconv, dim3(97),          dim3(256), 0, stream, phit);
    hipLaunchKernelGGL(k_ydft,   dim3(1024),        dim3(256), 0, stream, preal, pimag, gvar, phit, T);
    hipLaunchKernelGGL(k_xdft,   dim3(128, 4),      dim3(256), 0, stream, T, gh);
    hipLaunchKernelGGL(k_sample, dim3(NPTS/64),     dim3(256), 0, stream, (const float2*)coord, gh, out);
}